// Round 2
// baseline (578.042 us; speedup 1.0000x reference)
//
#include <hip/hip_runtime.h>
#include <hip/hip_bf16.h>

// Match numpy: no FMA contraction anywhere that feeds the Jacobi argmax.
#pragma clang fp contract(off)

#define N 4096
#define CIN 64
#define COUT 64
#define RR 4
#define ITERS 10

// deg[i] = count of i in row array (first E entries of edge_index flat)
__global__ void count_deg_k(const int* __restrict__ ei, float* __restrict__ deg, int E) {
    int e = blockIdx.x * 256 + threadIdx.x;
    if (e < E) atomicAdd(&deg[ei[e]], 1.0f);
}

// A[row,col] += 1 (counts; exact small integers in f32)
__global__ void scatter_k(const int* __restrict__ ei, float* __restrict__ a, int E) {
    int e = blockIdx.x * 256 + threadIdx.x;
    if (e < E) {
        int r = ei[e];
        int c = ei[E + e];
        atomicAdd(&a[(unsigned)r * N + c], 1.0f);
    }
}

__global__ void dinv_k(const float* __restrict__ deg, float* __restrict__ dinv) {
    int i = blockIdx.x * 256 + threadIdx.x;
    if (i < N) {
        float d = deg[i];
        dinv[i] = (d > 0.0f) ? (1.0f / sqrtf(d)) : 0.0f;  // correctly-rounded div+sqrt = numpy
    }
}

// a[i,j] = (i==j ? 1 : 0) - (dinv[i]*A_ij)*dinv[j]   (exact numpy op order)
__global__ void form_L_k(float* __restrict__ a, const float* __restrict__ dinv) {
    unsigned idx = blockIdx.x * 256u + threadIdx.x;
    unsigned i = idx >> 12, j = idx & 4095u;
    float v = a[idx];
    float m = (dinv[i] * v) * dinv[j];
    a[idx] = ((i == j) ? 1.0f : 0.0f) - m;
}

__global__ void init_y_k(const float* __restrict__ x, float* __restrict__ y) {
    int idx = blockIdx.x * 256 + threadIdx.x;
    if (idx < N * CIN) y[idx] = x[idx];
}

// Stage 1: block-level argmax of where(j>i, |a|, 0), first-occurrence (min flat idx) on ties.
__global__ void amax1_k(const float* __restrict__ a, float* __restrict__ pval, int* __restrict__ pidx) {
    int t = threadIdx.x;
    unsigned base = blockIdx.x * 16384u;
    float bv = -1.0f;
    int bi = 0;
    for (int s = 0; s < 64; ++s) {
        unsigned idx = base + (unsigned)s * 256u + t;   // increasing per thread -> strict > keeps first
        unsigned i = idx >> 12, j = idx & 4095u;
        float v = (j > i) ? fabsf(a[idx]) : 0.0f;
        if (v > bv) { bv = v; bi = (int)idx; }
    }
    __shared__ float sv[256];
    __shared__ int si[256];
    sv[t] = bv; si[t] = bi;
    __syncthreads();
    for (int off = 128; off > 0; off >>= 1) {
        if (t < off) {
            float v2 = sv[t + off]; int i2 = si[t + off];
            if (v2 > sv[t] || (v2 == sv[t] && i2 < si[t])) { sv[t] = v2; si[t] = i2; }
        }
        __syncthreads();
    }
    if (t == 0) { pval[blockIdx.x] = sv[0]; pidx[blockIdx.x] = si[0]; }
}

// Stage 2: final reduce over 1024 partials, then compute rotation params exactly as reference.
__global__ void amax2_k(const float* __restrict__ pval, const int* __restrict__ pidx,
                        const float* __restrict__ a,
                        int* __restrict__ rotk, int* __restrict__ rotl,
                        float* __restrict__ rotc, float* __restrict__ rotsv, int it) {
    int t = threadIdx.x;
    float bv = -1.0f;
    int bi = 0;
    for (int s = 0; s < 4; ++s) {
        int p = s * 256 + t;
        float v = pval[p]; int i2 = pidx[p];
        if (v > bv || (v == bv && i2 < bi)) { bv = v; bi = i2; }
    }
    __shared__ float sv[256];
    __shared__ int si[256];
    sv[t] = bv; si[t] = bi;
    __syncthreads();
    for (int off = 128; off > 0; off >>= 1) {
        if (t < off) {
            float v2 = sv[t + off]; int i2 = si[t + off];
            if (v2 > sv[t] || (v2 == sv[t] && i2 < si[t])) { sv[t] = v2; si[t] = i2; }
        }
        __syncthreads();
    }
    if (t == 0) {
        int k = si[0] >> 12;
        int l = si[0] & 4095;
        float akl = a[(unsigned)k * N + l];
        float aDiff = a[(unsigned)l * N + l] - a[(unsigned)k * N + k];
        float akl_safe = (akl == 0.0f) ? 1.0f : akl;
        float aDiff_safe = (aDiff == 0.0f) ? 1.0f : aDiff;
        float phi = aDiff / (2.0f * akl_safe);
        float t2 = 1.0f / (fabsf(phi) + sqrtf(phi * phi + 1.0f));
        t2 = (phi < 0.0f) ? -t2 : t2;
        float t1 = akl / aDiff_safe;
        float tt = (fabsf(akl) < fabsf(aDiff) * 1e-36f) ? t1 : t2;
        float cv = 1.0f / sqrtf(tt * tt + 1.0f);
        float sval = tt * cv;
        rotk[it] = k; rotl[it] = l; rotc[it] = cv; rotsv[it] = sval;
    }
}

// Column update of a (all rows i), plus incremental U^T x: mix rows k,l of y (G^T).
__global__ void colup_k(float* __restrict__ a, float* __restrict__ y,
                        const int* __restrict__ rotk, const int* __restrict__ rotl,
                        const float* __restrict__ rotc, const float* __restrict__ rotsv, int it) {
    int i = blockIdx.x * 256 + threadIdx.x;
    int k = rotk[it], l = rotl[it];
    float c = rotc[it], s = rotsv[it];
    if (i < N) {
        float ck = a[(unsigned)i * N + k];
        float cl = a[(unsigned)i * N + l];
        a[(unsigned)i * N + k] = c * ck - s * cl;
        a[(unsigned)i * N + l] = s * ck + c * cl;
    }
    if (i < CIN) {
        float yk = y[k * CIN + i];
        float yl = y[l * CIN + i];
        y[k * CIN + i] = c * yk - s * yl;   // (G^T y)[k] = c*yk - s*yl
        y[l * CIN + i] = s * yk + c * yl;   // (G^T y)[l] = s*yk + c*yl
    }
}

// Row update of a (reads post-column values), then zero a[k,l], a[l,k].
__global__ void rowup_k(float* __restrict__ a,
                        const int* __restrict__ rotk, const int* __restrict__ rotl,
                        const float* __restrict__ rotc, const float* __restrict__ rotsv, int it) {
    int j = blockIdx.x * 256 + threadIdx.x;
    if (j < N) {
        int k = rotk[it], l = rotl[it];
        float c = rotc[it], s = rotsv[it];
        float rk = a[(unsigned)k * N + j];
        float rl = a[(unsigned)l * N + j];
        float nk = c * rk - s * rl;
        float nl = s * rk + c * rl;
        if (j == l) nk = 0.0f;
        if (j == k) nl = 0.0f;
        a[(unsigned)k * N + j] = nk;
        a[(unsigned)l * N + j] = nl;
    }
}

// z[n,o] = sum_i ( c[o,i] + sum_j rw[o,i,j]*cos((j+1)*a2) - iw[o,i,j]*sin((j+1)*a2) ) * aux[n,i]
// where a2 = hw>EPS ? 2*atan(1/hw) : 2, hw = h[o,i]*w[n], w[n]=a[n,n], aux = y.
__global__ void spectral_k(const float* __restrict__ a, const float* __restrict__ y,
                           const float* __restrict__ hh, const float* __restrict__ rw,
                           const float* __restrict__ iw, const float* __restrict__ cw,
                           float* __restrict__ z) {
    int o = threadIdx.x;   // 0..63
    int n = blockIdx.x;    // 0..4095
    __shared__ float saux[CIN];
    saux[o] = y[n * CIN + o];
    __syncthreads();
    float wn = a[(unsigned)n * 4097u];   // diagonal
    float acc = 0.0f;
    for (int i = 0; i < CIN; ++i) {
        float hv = hh[o * CIN + i];
        float hw = hv * wn;
        float a2 = (hw > 1e-5f) ? (2.0f * atanf(1.0f / hw)) : 2.0f;
        float g = cw[o * CIN + i];
#pragma unroll
        for (int j = 0; j < RR; ++j) {
            float th = a2 * (float)(j + 1);
            float sn, cs;
            __sincosf(th, &sn, &cs);
            g += rw[(o * CIN + i) * RR + j] * cs
               - iw[(o * CIN + i) * RR + j] * sn;
        }
        acc += g * saux[i];
    }
    z[(unsigned)n * COUT + o] = acc;
}

// output = U @ out.T : apply G_10 ... G_1 to z rows (each thread owns one column -> independent).
__global__ void finalrot_k(float* __restrict__ z,
                           const int* __restrict__ rotk, const int* __restrict__ rotl,
                           const float* __restrict__ rotc, const float* __restrict__ rotsv) {
    int col = threadIdx.x;  // 0..63
    for (int i = ITERS - 1; i >= 0; --i) {
        int k = rotk[i], l = rotl[i];
        float c = rotc[i], s = rotsv[i];
        float zk = z[k * COUT + col];
        float zl = z[l * COUT + col];
        z[k * COUT + col] = c * zk + s * zl;   // (G z)[k]
        z[l * COUT + col] = -s * zk + c * zl;  // (G z)[l]
    }
}

__global__ void store_k(const float* __restrict__ z, const float* __restrict__ bias,
                        float* __restrict__ out) {
    int idx = blockIdx.x * 256 + threadIdx.x;
    if (idx < N * COUT) {
        int o = idx & 63;
        out[idx] = z[idx] + bias[o];
    }
}

extern "C" void kernel_launch(void* const* d_in, const int* in_sizes, int n_in,
                              void* d_out, int out_size, void* d_ws, size_t ws_size,
                              hipStream_t stream) {
    const float* x   = (const float*)d_in[0];
    const int*   ei  = (const int*)d_in[1];
    const float* rw  = (const float*)d_in[2];
    const float* iw  = (const float*)d_in[3];
    const float* hh  = (const float*)d_in[4];
    const float* cw  = (const float*)d_in[5];
    const float* bias= (const float*)d_in[6];
    float* out = (float*)d_out;

    // Workspace carve (~66.2 MB total)
    float* a    = (float*)d_ws;            // 16777216 f32 (64 MB) dense working matrix
    float* deg  = a + (size_t)N * N;       // 4096
    float* dinv = deg + N;                 // 4096
    float* y    = dinv + N;                // 262144 : U^T x (incrementally rotated)
    float* z    = y + N * CIN;             // 262144 : out.T then U*out.T
    float* pval = z + N * COUT;            // 1024 argmax partial values
    int*   pidx = (int*)(pval + 1024);     // 1024 argmax partial indices
    int*   rotk = pidx + 1024;             // 16
    int*   rotl = rotk + 16;               // 16
    float* rotc = (float*)(rotl + 16);     // 16
    float* rotsv= rotc + 16;               // 16

    int E = in_sizes[1] / 2;               // 200000 rows (after symmetric concat)

    // zero a and deg in one memset (contiguous)
    hipMemsetAsync(a, 0, ((size_t)N * N + N) * sizeof(float), stream);

    int eb = (E + 255) / 256;
    count_deg_k<<<eb, 256, 0, stream>>>(ei, deg, E);
    scatter_k<<<eb, 256, 0, stream>>>(ei, a, E);
    dinv_k<<<16, 256, 0, stream>>>(deg, dinv);
    form_L_k<<<(N * N) / 256, 256, 0, stream>>>(a, dinv);
    init_y_k<<<(N * CIN) / 256, 256, 0, stream>>>(x, y);

    for (int it = 0; it < ITERS; ++it) {
        amax1_k<<<1024, 256, 0, stream>>>(a, pval, pidx);
        amax2_k<<<1, 256, 0, stream>>>(pval, pidx, a, rotk, rotl, rotc, rotsv, it);
        colup_k<<<N / 256, 256, 0, stream>>>(a, y, rotk, rotl, rotc, rotsv, it);
        rowup_k<<<N / 256, 256, 0, stream>>>(a, rotk, rotl, rotc, rotsv, it);
    }

    spectral_k<<<N, 64, 0, stream>>>(a, y, hh, rw, iw, cw, z);
    finalrot_k<<<1, 64, 0, stream>>>(z, rotk, rotl, rotc, rotsv);
    store_k<<<(N * COUT) / 256, 256, 0, stream>>>(z, bias, out);
}